// Round 6
// baseline (3522.528 us; speedup 1.0000x reference)
//
#include <hip/hip_runtime.h>
#include <hip/hip_bf16.h>

// GRU last-hidden: B=64, T=512, I=256, H=512, fp32 in/out.
// Persistent kernel: 64 WGs x 256 thr (R5 config). WG w owns h-cols
// [8w,8w+8); weights live in VGPR MFMA fragments for the whole kernel.
//
// Round-11. Post-mortem R9/R10: identical absmax 0.711 = all-zero output =
// vote state in ws was STALE (ws persists across launches; "harness zeroes
// ws" was an unverified assumption) -> all WGs exited. Also R6 showed the
// step time responds to exchange VOLUME (2x packets -> +1.2us/step): the
// 4MB/step all-to-all sc1 read burst is the bottleneck, not protocol RT.
// This round:
//  * REPLAY-SAFE init barrier: each WG flags its post-prologue
//    s_memrealtime (global monotone); readers spin until flag >= own
//    entry time. Stale flags are always older than this launch's start.
//  * TAGGED FAST PATH: producers publish BOTH the R5-classic 16B bf16
//    packets (+tag array) AND 32B dwords (epoch|step)<<16|bf16 in a D=4
//    ring (sc1 stores). Consumers try plain CACHED loads + buffer_inv sc0
//    + exact-tag validation (per-dword atomicity => no tearing; epoch
//    from the barrier leader's timestamp kills cross-launch relics; own
//    fragment substituted from LDS, R6-proven). Hit => exchange served
//    from XCD-local L2 (~8x less L3 burst + ~200cy vs ~2000cy). Miss =>
//    proven R5 classic (tag poll + 16B sc1). 4 consecutive misses =>
//    demote permanently => floor ~= R5's 1.79ms.
//  * Back-pressure: per-(wave,wg) progress array (validated step), gating
//    ring overwrite with slack-3 (off critical path); restores the
//    overwrite-safety induction for both paths.
//  * x converted on the fly (v_cvt_pk_bf16_f32, RNE) - no 16MB xb; ws use
//    drops to ~800KB (well under proven budget).

#define NB 64
#define NT 512
#define NI 256
#define NH 512

typedef __attribute__((ext_vector_type(8))) short bf16x8;
typedef __attribute__((ext_vector_type(4))) float f32x4;
typedef __attribute__((ext_vector_type(4))) int i32x4;
typedef __attribute__((ext_vector_type(4))) unsigned u32x4;

static __device__ __forceinline__ short f2b(float f) {
  unsigned u = __builtin_bit_cast(unsigned, f);
  unsigned r = (u + 0x7fffu + ((u >> 16) & 1u)) >> 16;
  return (short)r;
}
static __device__ __forceinline__ float sigm(float x) {
  return 1.0f / (1.0f + __expf(-x));
}
static __device__ __forceinline__ float tanh_f(float x) {
  return 1.0f - 2.0f / (__expf(2.0f * x) + 1.0f);
}

__global__ __launch_bounds__(256, 1)
void gru_persistent(const float* __restrict__ x,
                    const float* __restrict__ Wih,
                    const float* __restrict__ Whh,
                    const float* __restrict__ bih,
                    const float* __restrict__ bhh,
                    float* __restrict__ out,
                    unsigned char* __restrict__ ws) {
  const int wg   = blockIdx.x;    // 0..63 : owns h-cols [8wg, 8wg+8)
  const int tid  = threadIdx.x;   // 0..255
  const int wave = tid >> 6;      // 0..3  : owns batches [16*wave, +16)
  const int lane = tid & 63;
  const int c    = lane & 15;     // tile col / A-row index
  const int q    = lane >> 4;     // quad: k-group (A/B), row-group (C/D)

  // ws layout (~800KB): flags u64[64] @0 (stride 64B); prog int[4][64]
  // @4K; tags int[4][64] @8K; ringC bf16 [4 slots][64wg][64b][8] @16K
  // (4x64KB); ringT u32 tagged [4][64][64][8] @16K+256K (4x128KB).
  unsigned long long* flags = (unsigned long long*)ws;
  int* prog = (int*)(ws + 4096);
  int* tags = (int*)(ws + 8192);
  unsigned short* ringC = (unsigned short*)(ws + 16384);
  unsigned*       ringT = (unsigned*)(ws + 16384 + 262144);

  __shared__ __align__(16) unsigned short trans[4][16][8];  // per-wave bounce

  const unsigned long long t0 = __builtin_amdgcn_s_memrealtime();

  // ---- prologue: zero ringC slot0 (h0=0), tags, prog ----
  ((unsigned*)ringC)[wg * 256 + tid] = 0u;      // 64KB = 16384 dwords
  if (wg == 0) { tags[tid] = 0; prog[tid] = 0; }

  // ---- loop-invariant weight fragments into registers ----
  bf16x8 wh[2][16];  // W_hh, K=512 -> 16 k-steps
  bf16x8 wi[2][8];   // W_ih, K=256 -> 8 k-steps
#pragma unroll
  for (int nt = 0; nt < 2; nt++) {
    int nl = nt * 16 + c;
    bool valid = nl < 24;
    int gate = nl >> 3;
    int jj = nl & 7;
    int grow = valid ? (gate * NH + wg * 8 + jj) : 0;
#pragma unroll
    for (int kk = 0; kk < 16; kk++) {
      const float* p = Whh + (size_t)grow * NH + kk * 32 + q * 8;
      bf16x8 f;
#pragma unroll
      for (int e = 0; e < 8; e++) f[e] = valid ? f2b(p[e]) : (short)0;
      wh[nt][kk] = f;
    }
#pragma unroll
    for (int kk = 0; kk < 8; kk++) {
      const float* p = Wih + (size_t)grow * NI + kk * 32 + q * 8;
      bf16x8 f;
#pragma unroll
      for (int e = 0; e < 8; e++) f[e] = valid ? f2b(p[e]) : (short)0;
      wi[nt][kk] = f;
    }
  }

  const int jcol = wg * 8 + (c & 7);
  const float bri = bih[jcol],          brh = bhh[jcol];
  const float bzi = bih[NH + jcol],     bzh = bhh[NH + jcol];
  const float bni = bih[2 * NH + jcol], bnh = bhh[2 * NH + jcol];

  float hold[4] = {0.f, 0.f, 0.f, 0.f};  // fp32 master state (c<8 lanes)

  // ---- REPLAY-SAFE init barrier (timestamp flags) ----
  // Flag = post-prologue realtime, RELEASE (forces L2 writeback of the
  // plain prologue stores). Reader passes only if flag >= its own entry
  // time: stale flags (prev launch, pre-dates this launch) always block;
  // fresh flags pass (prologue+weights >> dispatch skew).
  __syncthreads();
  if (tid == 0)
    __hip_atomic_store(&flags[wg * 8], __builtin_amdgcn_s_memrealtime(),
                       __ATOMIC_RELEASE, __HIP_MEMORY_SCOPE_AGENT);
  if (wave == 0) {
    while (__hip_atomic_load(&flags[lane * 8], __ATOMIC_RELAXED,
                             __HIP_MEMORY_SCOPE_AGENT) < t0)
      __builtin_amdgcn_s_sleep(1);
  }
  __syncthreads();
  __threadfence();  // acquire: invalidate L1/L2 for fresh init data

  // launch epoch from leader's flag (same value seen by all WGs; 7 bits,
  // ~164us granularity -> consecutive launches always differ).
  const unsigned long long f0 =
      __hip_atomic_load(&flags[0], __ATOMIC_RELAXED, __HIP_MEMORY_SCOPE_AGENT);
  const unsigned epoch = (unsigned)((f0 >> 14) & 0x7Full);

  const int b0 = wave * 16 + c;
  int* myprog = prog + wave * 64;
  int* mytags = tags + wave * 64;
  const int* tagp  = mytags + lane;   // classic poll addr (lane -> wg)
  const int* progp = myprog + lane;   // back-pressure gate addr

  const int kk_own = wg >> 2;         // fast path: fragment with own cols
  const bool own   = (q == (wg & 3));

  bool fastMode = true;
  int  streak   = 0;

  for (int t = 0; t < NT; t++) {
    const int slot = t & 3, nslot = (t + 1) & 3;
    const unsigned short* rc = ringC + (size_t)slot * 32768;
    const unsigned*       rt = ringT + (size_t)slot * 32768;
    unsigned short* rcn = ringC + (size_t)nslot * 32768;
    unsigned*       rtn = ringT + (size_t)nslot * 32768;

    f32x4 aX0 = {0.f,0.f,0.f,0.f}, aX1 = {0.f,0.f,0.f,0.f};
    f32x4 aH0 = {0.f,0.f,0.f,0.f}, aH1 = {0.f,0.f,0.f,0.f};

    // x-projection straight from fp32 x (cvt_pk = RNE, same as f2b).
    const float* xrow = x + ((size_t)b0 * NT + t) * NI;
#pragma unroll
    for (int kk = 0; kk < 8; kk++) {
      const float4* xp = (const float4*)(xrow + kk * 32 + q * 8);
      float4 u0 = xp[0], u1 = xp[1];
      unsigned d0, d1, d2, d3;
      asm("v_cvt_pk_bf16_f32 %0, %1, %2" : "=v"(d0) : "v"(u0.x), "v"(u0.y));
      asm("v_cvt_pk_bf16_f32 %0, %1, %2" : "=v"(d1) : "v"(u0.z), "v"(u0.w));
      asm("v_cvt_pk_bf16_f32 %0, %1, %2" : "=v"(d2) : "v"(u1.x), "v"(u1.y));
      asm("v_cvt_pk_bf16_f32 %0, %1, %2" : "=v"(d3) : "v"(u1.z), "v"(u1.w));
      u32x4 pk = {d0, d1, d2, d3};
      bf16x8 a = __builtin_bit_cast(bf16x8, pk);
      aX0 = __builtin_amdgcn_mfma_f32_16x16x32_bf16(a, wi[0][kk], aX0, 0, 0, 0);
      aX1 = __builtin_amdgcn_mfma_f32_16x16x32_bf16(a, wi[1][kk], aX1, 0, 0, 0);
    }

    // back-pressure gate load (needed only at publish): issue early.
    int pv = 0;
    if (t < NT - 1)
      asm volatile("global_load_dword %0, %1, off sc1" : "=v"(pv) : "v"(progp));

    bool done = false;

    if (t > 0 && fastMode) {
      // ---- FAST: L1 inv + plain cached 32B loads + exact-tag validate --
      asm volatile("buffer_inv sc0" ::: "memory");
      i32x4 hv[16][2];
#pragma unroll
      for (int kk = 0; kk < 16; kk++) {
        const void* ap = (const char*)rt + (size_t)(((kk*4+q)*64 + b0) << 5);
        asm volatile("global_load_dwordx4 %0, %1, off"
                     : "=v"(hv[kk][0]) : "v"(ap));
        asm volatile("global_load_dwordx4 %0, %1, off offset:16"
                     : "=v"(hv[kk][1]) : "v"(ap));
      }
      asm volatile("s_waitcnt vmcnt(0)"
          : "+v"(hv[0][0]), "+v"(hv[0][1]), "+v"(hv[1][0]), "+v"(hv[1][1]),
            "+v"(hv[2][0]), "+v"(hv[2][1]), "+v"(hv[3][0]), "+v"(hv[3][1]),
            "+v"(hv[4][0]), "+v"(hv[4][1]), "+v"(hv[5][0]), "+v"(hv[5][1]),
            "+v"(hv[6][0]), "+v"(hv[6][1]), "+v"(hv[7][0]), "+v"(hv[7][1])
          :: "memory");
      asm volatile("s_waitcnt vmcnt(0)"
          : "+v"(hv[8][0]),  "+v"(hv[8][1]),  "+v"(hv[9][0]),  "+v"(hv[9][1]),
            "+v"(hv[10][0]), "+v"(hv[10][1]), "+v"(hv[11][0]), "+v"(hv[11][1]),
            "+v"(hv[12][0]), "+v"(hv[12][1]), "+v"(hv[13][0]), "+v"(hv[13][1]),
            "+v"(hv[14][0]), "+v"(hv[14][1]), "+v"(hv[15][0]), "+v"(hv[15][1]),
            "+v"(pv)
          :: "memory");

      const unsigned want   = (epoch << 9) | (unsigned)t;  // tag of h_t
      const unsigned wanthi = want << 16;

      // own-fragment from LDS (own stores may not be self-visible), tagged
      const unsigned* lp = (const unsigned*)&trans[wave][c][0];
      unsigned lw0 = lp[0], lw1 = lp[1], lw2 = lp[2], lw3 = lp[3];
      unsigned td0 = wanthi | (lw0 & 0xffffu), td1 = wanthi | (lw0 >> 16);
      unsigned td2 = wanthi | (lw1 & 0xffffu), td3 = wanthi | (lw1 >> 16);
      unsigned td4 = wanthi | (lw2 & 0xffffu), td5 = wanthi | (lw2 >> 16);
      unsigned td6 = wanthi | (lw3 & 0xffffu), td7 = wanthi | (lw3 >> 16);
#pragma unroll
      for (int kk = 0; kk < 16; kk++) {
        if (kk == kk_own) {
          hv[kk][0][0] = own ? (int)td0 : hv[kk][0][0];
          hv[kk][0][1] = own ? (int)td1 : hv[kk][0][1];
          hv[kk][0][2] = own ? (int)td2 : hv[kk][0][2];
          hv[kk][0][3] = own ? (int)td3 : hv[kk][0][3];
          hv[kk][1][0] = own ? (int)td4 : hv[kk][1][0];
          hv[kk][1][1] = own ? (int)td5 : hv[kk][1][1];
          hv[kk][1][2] = own ? (int)td6 : hv[kk][1][2];
          hv[kk][1][3] = own ? (int)td7 : hv[kk][1][3];
        }
      }
      unsigned acc = 0;
#pragma unroll
      for (int kk = 0; kk < 16; kk++)
#pragma unroll
        for (int h2 = 0; h2 < 2; h2++)
#pragma unroll
          for (int j2 = 0; j2 < 4; j2++)
            acc |= ((unsigned)hv[kk][h2][j2] >> 16) ^ want;

      if (__all((int)(acc == 0))) {
        streak = 0;
        if (lane == 0) {  // progress = validated h_t
          int* pp = myprog + wg; int v2 = t + 1;
          asm volatile("global_store_dword %0, %1, off sc1"
                       :: "v"(pp), "v"(v2) : "memory");
        }
        // extract bf16 + h-projection (per-kk, frees hv progressively)
#pragma unroll
        for (int kk = 0; kk < 16; kk++) {
          unsigned w0 = __builtin_amdgcn_perm((unsigned)hv[kk][0][1],
                                              (unsigned)hv[kk][0][0], 0x05040100u);
          unsigned w1 = __builtin_amdgcn_perm((unsigned)hv[kk][0][3],
                                              (unsigned)hv[kk][0][2], 0x05040100u);
          unsigned w2 = __builtin_amdgcn_perm((unsigned)hv[kk][1][1],
                                              (unsigned)hv[kk][1][0], 0x05040100u);
          unsigned w3 = __builtin_amdgcn_perm((unsigned)hv[kk][1][3],
                                              (unsigned)hv[kk][1][2], 0x05040100u);
          u32x4 pk2 = {w0, w1, w2, w3};
          bf16x8 a = __builtin_bit_cast(bf16x8, pk2);
          aH0 = __builtin_amdgcn_mfma_f32_16x16x32_bf16(a, wh[0][kk], aH0, 0,0,0);
          aH1 = __builtin_amdgcn_mfma_f32_16x16x32_bf16(a, wh[1][kk], aH1, 0,0,0);
        }
        done = true;
      } else {
        if (++streak >= 4) fastMode = false;  // persistent staleness: demote
      }
    }

    if (!done) {
      // ---- CLASSIC (R5-proven): tag poll + 16B sc1 loads ----
      if (t > 0) {
        const int need = t + 1;
        for (;;) {
          int v;
          asm volatile("global_load_dword %0, %1, off sc1"
                       : "=v"(v) : "v"(tagp));
          asm volatile("s_waitcnt vmcnt(0)" : "+v"(v), "+v"(pv) :: "memory");
          if (__all(v >= need)) break;
        }
      }
      i32x4 hc[16];
#pragma unroll
      for (int kk = 0; kk < 16; kk++) {
        const void* ap = (const char*)rc + (size_t)(((kk*4+q)*64 + b0) << 4);
        asm volatile("global_load_dwordx4 %0, %1, off sc1"
                     : "=v"(hc[kk]) : "v"(ap));
      }
      asm volatile("s_waitcnt vmcnt(0)"
          : "+v"(hc[0]), "+v"(hc[1]), "+v"(hc[2]), "+v"(hc[3]),
            "+v"(hc[4]), "+v"(hc[5]), "+v"(hc[6]), "+v"(hc[7]),
            "+v"(hc[8]), "+v"(hc[9]), "+v"(hc[10]), "+v"(hc[11]),
            "+v"(hc[12]), "+v"(hc[13]), "+v"(hc[14]), "+v"(hc[15]),
            "+v"(pv)
          :: "memory");
      if (lane == 0) {
        int* pp = myprog + wg; int v2 = t + 1;
        asm volatile("global_store_dword %0, %1, off sc1"
                     :: "v"(pp), "v"(v2) : "memory");
      }
#pragma unroll
      for (int kk = 0; kk < 16; kk++) {
        bf16x8 a = __builtin_bit_cast(bf16x8, hc[kk]);
        aH0 = __builtin_amdgcn_mfma_f32_16x16x32_bf16(a, wh[0][kk], aH0, 0,0,0);
        aH1 = __builtin_amdgcn_mfma_f32_16x16x32_bf16(a, wh[1][kk], aH1, 0,0,0);
      }
    }

    // epilogue: C/D layout col=lane&15, row=q*4+reg. Lane c<8 owns col wg*8+c.
#pragma unroll
    for (int r = 0; r < 4; r++) {
      float xz = __shfl_xor(aX0[r], 8, 64);
      float hz = __shfl_xor(aH0[r], 8, 64);
      float rr = sigm(aX0[r] + bri + aH0[r] + brh);
      float zz = sigm(xz + bzi + hz + bzh);
      float nn = tanh_f(aX1[r] + bni + rr * (aH1[r] + bnh));
      float hv2 = (1.0f - zz) * nn + zz * hold[r];
      hold[r] = hv2;
      if (c < 8) trans[wave][q * 4 + r][c] = (unsigned short)f2b(hv2);
    }

    if (t < NT - 1) {
      // overwrite gate: nslot held h_{t-3}; need all consumers past it
      // (prog >= t-2). pv issued early -> usually satisfied, no spin.
      {
        const int need = t - 2;
        while (!__all(pv >= need)) {
          asm volatile("global_load_dword %0, %1, off sc1"
                       : "=v"(pv) : "v"(progp));
          asm volatile("s_waitcnt vmcnt(0)" : "+v"(pv) :: "memory");
        }
      }
      asm volatile("s_waitcnt lgkmcnt(0)" ::: "memory");
      if (lane < 16) {
        int b = wave * 16 + lane;
        const unsigned* tp = (const unsigned*)&trans[wave][lane][0];
        unsigned s0 = tp[0], s1 = tp[1], s2 = tp[2], s3 = tp[3];
        // classic 16B packet
        i32x4 pk = *(const i32x4*)tp;
        void* dc = (char*)rcn + ((size_t)(wg * 64 + b) << 4);
        asm volatile("global_store_dwordx4 %0, %1, off sc1"
                     :: "v"(dc), "v"(pk) : "memory");
        // tagged 32B packet (tag of h_{t+1})
        unsigned tg = (((epoch << 9) | (unsigned)(t + 1)) << 16);
        i32x4 lo, hi;
        lo[0] = (int)(tg | (s0 & 0xffffu)); lo[1] = (int)(tg | (s0 >> 16));
        lo[2] = (int)(tg | (s1 & 0xffffu)); lo[3] = (int)(tg | (s1 >> 16));
        hi[0] = (int)(tg | (s2 & 0xffffu)); hi[1] = (int)(tg | (s2 >> 16));
        hi[2] = (int)(tg | (s3 & 0xffffu)); hi[3] = (int)(tg | (s3 >> 16));
        void* dt = (char*)rtn + ((size_t)(wg * 64 + b) << 5);
        asm volatile("global_store_dwordx4 %0, %1, off sc1"
                     :: "v"(dt), "v"(lo) : "memory");
        asm volatile("global_store_dwordx4 %0, %1, off offset:16 sc1"
                     :: "v"(dt), "v"(hi) : "memory");
      }
      // drain data, then classic tag (certifies 16B data at L3).
      asm volatile("s_waitcnt vmcnt(0)" ::: "memory");
      if (lane == 0) {
        int* tp2 = mytags + wg; int tv2 = t + 2;
        asm volatile("global_store_dword %0, %1, off sc1"
                     :: "v"(tp2), "v"(tv2) : "memory");
      }
    }
  }

  // final h (fp32 master copy) -> d_out
  if (c < 8) {
#pragma unroll
    for (int r = 0; r < 4; r++) {
      int b = wave * 16 + q * 4 + r;
      out[(size_t)b * NH + wg * 8 + c] = hold[r];
    }
  }
}

extern "C" void kernel_launch(void* const* d_in, const int* in_sizes, int n_in,
                              void* d_out, int out_size, void* d_ws, size_t ws_size,
                              hipStream_t stream) {
  const float* x   = (const float*)d_in[0];
  const float* Wih = (const float*)d_in[1];
  const float* Whh = (const float*)d_in[2];
  const float* bih = (const float*)d_in[3];
  const float* bhh = (const float*)d_in[4];
  float* out = (float*)d_out;
  hipLaunchKernelGGL(gru_persistent, dim3(NB), dim3(256), 0, stream,
                     x, Wih, Whh, bih, bhh, out, (unsigned char*)d_ws);
}